// Round 1
// baseline (382.777 us; speedup 1.0000x reference)
//
#include <hip/hip_runtime.h>
#include <stdint.h>

// ---------------------------------------------------------------------------
// JAX Threefry-2x32 (20 rounds), key = jax.random.key(42) -> (k0,k1) = (0,42)
// ---------------------------------------------------------------------------
__device__ __forceinline__ unsigned int rotl32(unsigned int x, unsigned int d) {
    return (x << d) | (x >> (32u - d));
}

__device__ __forceinline__ void threefry2x32_key0_42(unsigned int c0, unsigned int c1,
                                                     unsigned int& o0, unsigned int& o1) {
    const unsigned int ks0 = 0u;
    const unsigned int ks1 = 42u;
    const unsigned int ks2 = 0x1BD11BDAu ^ 0u ^ 42u;
    unsigned int x0 = c0 + ks0;
    unsigned int x1 = c1 + ks1;
#define TF_RND(r) { x0 += x1; x1 = rotl32(x1, (r)); x1 ^= x0; }
    TF_RND(13) TF_RND(15) TF_RND(26) TF_RND(6)
    x0 += ks1; x1 += ks2 + 1u;
    TF_RND(17) TF_RND(29) TF_RND(16) TF_RND(24)
    x0 += ks2; x1 += ks0 + 2u;
    TF_RND(13) TF_RND(15) TF_RND(26) TF_RND(6)
    x0 += ks0; x1 += ks1 + 3u;
    TF_RND(17) TF_RND(29) TF_RND(16) TF_RND(24)
    x0 += ks1; x1 += ks2 + 4u;
    TF_RND(13) TF_RND(15) TF_RND(26) TF_RND(6)
    x0 += ks2; x1 += ks0 + 5u;
#undef TF_RND
    o0 = x0; o1 = x1;
}

// jax_threefry_partitionable=True path (modern JAX default), bit_width=32:
//   counts = iota(uint64); bits[n] = o0 ^ o1 with counter (hi=0, lo=n)
// uniform: bitcast((bits >> 9) | 0x3F800000) - 1.0, clamped to >= 0
__device__ __forceinline__ float jax_uniform_u01(unsigned int n) {
    unsigned int o0, o1;
    threefry2x32_key0_42(0u, n, o0, o1);
    unsigned int bits = o0 ^ o1;
    unsigned int fb = (bits >> 9) | 0x3F800000u;
    float u = __uint_as_float(fb) - 1.0f;
    return fmaxf(u, 0.0f);
}

// ---------------------------------------------------------------------------
// Kernel 1: synaptic pulse kernel eps[j] = (1+tanh(t)) * exp(-t/tau_s)/tau_s
// ---------------------------------------------------------------------------
__global__ void eps_kernel(const float* __restrict__ tss,
                           const float* __restrict__ tau_s,
                           float* __restrict__ eps, int N) {
    int i = blockIdx.x * blockDim.x + threadIdx.x;
    if (i < N) {
        float t  = tss[i] - 1.0f;   // DELTA_DELAY = 1.0
        float ts = tau_s[i];
        eps[i] = (1.0f + tanhf(t)) * expf(-t / ts) / ts;
    }
}

// ---------------------------------------------------------------------------
// Kernel 2: one block per row. I_syn[row] = w[row,:]·eps - w[row,row]*eps[row],
// then the full per-neuron state update + Bernoulli sampling (thread 0).
// ---------------------------------------------------------------------------
__global__ __launch_bounds__(256) void row_update_kernel(
    const float* __restrict__ w,
    const float* __restrict__ eps,
    const float* __restrict__ I_ext,
    const float* __restrict__ v,
    const float* __restrict__ spiked,
    const float* __restrict__ tss,
    const float* __restrict__ theta_v,
    const float* __restrict__ tau_m,
    const float* __restrict__ tau_theta,
    const float* __restrict__ J_theta,
    const float* __restrict__ E_L,
    const float* __restrict__ c,
    const float* __restrict__ Delta_u,
    const float* __restrict__ theta_inf,
    float* __restrict__ out, int N) {

    const int row = blockIdx.x;
    const int tid = threadIdx.x;
    const float4* __restrict__ wrow = (const float4*)(w + (size_t)row * (size_t)N);
    const float4* __restrict__ e4   = (const float4*)eps;

    float acc = 0.0f;
    const int n4 = N >> 2;
    for (int idx = tid; idx < n4; idx += 256) {
        float4 wv = wrow[idx];
        float4 ev = e4[idx];
        acc += wv.x * ev.x + wv.y * ev.y + wv.z * ev.z + wv.w * ev.w;
    }

    // wave (64-lane) reduction, then cross-wave via LDS
    #pragma unroll
    for (int off = 32; off > 0; off >>= 1)
        acc += __shfl_down(acc, off, 64);

    __shared__ float wsum[4];
    const int wid  = tid >> 6;
    const int lane = tid & 63;
    if (lane == 0) wsum[wid] = acc;
    __syncthreads();

    if (tid == 0) {
        float I_syn = wsum[0] + wsum[1] + wsum[2] + wsum[3];
        // remove self-recurrence: W_syn has zero diagonal
        I_syn -= w[(size_t)row * (size_t)N + row] * eps[row];

        // adaptation threshold update
        float th = theta_v[row] +
                   (theta_inf[row] - theta_v[row] + J_theta[row] * spiked[row]) / tau_theta[row];
        // membrane potential update
        float v_next = v[row] + (E_L[row] - v[row] + I_ext[row]) / tau_m[row] + I_syn;

        float notref = (tss[row] > 2.0f) ? 1.0f : 0.0f;   // T_REFRACTORY = 2.0
        float lam = notref * c[row] * expf((v_next - th) / Delta_u[row]);
        lam = fminf(fmaxf(lam, 0.0f), 1.0f);

        float u = jax_uniform_u01((unsigned int)row);
        float s = (u < lam) ? 1.0f : 0.0f;
        float v_new = (1.0f - s) * v_next;                // RESET_POTENTIAL = 0

        out[row]         = lam;     // spikes_lambda
        out[N + row]     = s;       // spiked_new
        out[2 * N + row] = v_new;   // v_new
    }
}

extern "C" void kernel_launch(void* const* d_in, const int* in_sizes, int n_in,
                              void* d_out, int out_size, void* d_ws, size_t ws_size,
                              hipStream_t stream) {
    const int N = in_sizes[0];
    const float* I_ext     = (const float*)d_in[0];
    const float* w         = (const float*)d_in[1];
    const float* v         = (const float*)d_in[2];
    const float* spiked    = (const float*)d_in[3];
    const float* tss       = (const float*)d_in[4];
    const float* theta_v   = (const float*)d_in[5];
    const float* tau_m     = (const float*)d_in[6];
    const float* tau_s     = (const float*)d_in[7];
    const float* tau_theta = (const float*)d_in[8];
    const float* J_theta   = (const float*)d_in[9];
    const float* E_L       = (const float*)d_in[10];
    const float* c         = (const float*)d_in[11];
    const float* Delta_u   = (const float*)d_in[12];
    const float* theta_inf = (const float*)d_in[13];
    float* out = (float*)d_out;
    float* eps = (float*)d_ws;   // N floats of scratch

    hipLaunchKernelGGL(eps_kernel, dim3((N + 255) / 256), dim3(256), 0, stream,
                       tss, tau_s, eps, N);
    hipLaunchKernelGGL(row_update_kernel, dim3(N), dim3(256), 0, stream,
                       w, eps, I_ext, v, spiked, tss, theta_v, tau_m, tau_theta,
                       J_theta, E_L, c, Delta_u, theta_inf, out, N);
}

// Round 2
// 381.182 us; speedup vs baseline: 1.0042x; 1.0042x over previous
//
#include <hip/hip_runtime.h>
#include <stdint.h>

// ---------------------------------------------------------------------------
// JAX Threefry-2x32 (20 rounds), key = jax.random.key(42) -> (k0,k1) = (0,42)
// ---------------------------------------------------------------------------
__device__ __forceinline__ unsigned int rotl32(unsigned int x, unsigned int d) {
    return (x << d) | (x >> (32u - d));
}

__device__ __forceinline__ void threefry2x32_key0_42(unsigned int c0, unsigned int c1,
                                                     unsigned int& o0, unsigned int& o1) {
    const unsigned int ks0 = 0u;
    const unsigned int ks1 = 42u;
    const unsigned int ks2 = 0x1BD11BDAu ^ 0u ^ 42u;
    unsigned int x0 = c0 + ks0;
    unsigned int x1 = c1 + ks1;
#define TF_RND(r) { x0 += x1; x1 = rotl32(x1, (r)); x1 ^= x0; }
    TF_RND(13) TF_RND(15) TF_RND(26) TF_RND(6)
    x0 += ks1; x1 += ks2 + 1u;
    TF_RND(17) TF_RND(29) TF_RND(16) TF_RND(24)
    x0 += ks2; x1 += ks0 + 2u;
    TF_RND(13) TF_RND(15) TF_RND(26) TF_RND(6)
    x0 += ks0; x1 += ks1 + 3u;
    TF_RND(17) TF_RND(29) TF_RND(16) TF_RND(24)
    x0 += ks1; x1 += ks2 + 4u;
    TF_RND(13) TF_RND(15) TF_RND(26) TF_RND(6)
    x0 += ks2; x1 += ks0 + 5u;
#undef TF_RND
    o0 = x0; o1 = x1;
}

// jax_threefry_partitionable=True, bit_width=32: bits[n] = o0 ^ o1, counter (0, n)
// uniform: bitcast((bits >> 9) | 0x3F800000) - 1.0, clamped >= 0
__device__ __forceinline__ float jax_uniform_u01(unsigned int n) {
    unsigned int o0, o1;
    threefry2x32_key0_42(0u, n, o0, o1);
    unsigned int bits = o0 ^ o1;
    unsigned int fb = (bits >> 9) | 0x3F800000u;
    float u = __uint_as_float(fb) - 1.0f;
    return fmaxf(u, 0.0f);
}

// ---------------------------------------------------------------------------
// Kernel 1: eps[j] = (1+tanh(t)) * exp(-t/tau_s)/tau_s,  t = tss - DELTA_DELAY
// ---------------------------------------------------------------------------
__global__ void eps_kernel(const float* __restrict__ tss,
                           const float* __restrict__ tau_s,
                           float* __restrict__ eps, int N) {
    int i = blockIdx.x * blockDim.x + threadIdx.x;
    if (i < N) {
        float t  = tss[i] - 1.0f;   // DELTA_DELAY = 1.0
        float ts = tau_s[i];
        eps[i] = (1.0f + tanhf(t)) * expf(-t / ts) / ts;
    }
}

// ---------------------------------------------------------------------------
// Kernel 2: ONE WAVE PER ROW (4 rows per 256-thread block). No LDS, no
// __syncthreads. 32 float4 iters/lane, 4 independent accumulators for ILP,
// wave shuffle reduction, lane-0 epilogue (state update + Threefry Bernoulli).
// ---------------------------------------------------------------------------
__global__ __launch_bounds__(256) void row_update_kernel(
    const float* __restrict__ w,
    const float* __restrict__ eps,
    const float* __restrict__ I_ext,
    const float* __restrict__ v,
    const float* __restrict__ spiked,
    const float* __restrict__ tss,
    const float* __restrict__ theta_v,
    const float* __restrict__ tau_m,
    const float* __restrict__ tau_theta,
    const float* __restrict__ J_theta,
    const float* __restrict__ E_L,
    const float* __restrict__ c,
    const float* __restrict__ Delta_u,
    const float* __restrict__ theta_inf,
    float* __restrict__ out, int N) {

    const int wid  = threadIdx.x >> 6;        // wave id within block: 0..3
    const int lane = threadIdx.x & 63;
    const int row  = blockIdx.x * 4 + wid;
    if (row >= N) return;

    const float4* __restrict__ wrow = (const float4*)(w + (size_t)row * (size_t)N);
    const float4* __restrict__ e4   = (const float4*)eps;
    const int n4 = N >> 2;                    // float4 elements per row (2048)

    float a0 = 0.0f, a1 = 0.0f, a2 = 0.0f, a3 = 0.0f;
    int idx = lane;
    // main unrolled-by-4 loop: 8 loads in flight per lane, 4 indep FMA chains
    for (; idx + 192 < n4; idx += 256) {
        float4 w0 = wrow[idx];
        float4 w1 = wrow[idx + 64];
        float4 w2 = wrow[idx + 128];
        float4 w3 = wrow[idx + 192];
        float4 e0 = e4[idx];
        float4 e1 = e4[idx + 64];
        float4 e2 = e4[idx + 128];
        float4 e3 = e4[idx + 192];
        a0 = fmaf(w0.x, e0.x, fmaf(w0.y, e0.y, fmaf(w0.z, e0.z, fmaf(w0.w, e0.w, a0))));
        a1 = fmaf(w1.x, e1.x, fmaf(w1.y, e1.y, fmaf(w1.z, e1.z, fmaf(w1.w, e1.w, a1))));
        a2 = fmaf(w2.x, e2.x, fmaf(w2.y, e2.y, fmaf(w2.z, e2.z, fmaf(w2.w, e2.w, a2))));
        a3 = fmaf(w3.x, e3.x, fmaf(w3.y, e3.y, fmaf(w3.z, e3.z, fmaf(w3.w, e3.w, a3))));
    }
    for (; idx < n4; idx += 64) {             // remainder (none when N=8192)
        float4 wv = wrow[idx];
        float4 ev = e4[idx];
        a0 = fmaf(wv.x, ev.x, fmaf(wv.y, ev.y, fmaf(wv.z, ev.z, fmaf(wv.w, ev.w, a0))));
    }
    float acc = (a0 + a1) + (a2 + a3);

    // wave-wide (64-lane) butterfly reduction — no LDS, no barrier
    #pragma unroll
    for (int off = 32; off > 0; off >>= 1)
        acc += __shfl_down(acc, off, 64);

    if (lane == 0) {
        float I_syn = acc - w[(size_t)row * (size_t)N + row] * eps[row]; // zero diagonal

        float th = theta_v[row] +
                   (theta_inf[row] - theta_v[row] + J_theta[row] * spiked[row]) / tau_theta[row];
        float v_next = v[row] + (E_L[row] - v[row] + I_ext[row]) / tau_m[row] + I_syn;

        float notref = (tss[row] > 2.0f) ? 1.0f : 0.0f;   // T_REFRACTORY = 2.0
        float lam = notref * c[row] * expf((v_next - th) / Delta_u[row]);
        lam = fminf(fmaxf(lam, 0.0f), 1.0f);

        float u = jax_uniform_u01((unsigned int)row);
        float s = (u < lam) ? 1.0f : 0.0f;
        float v_new = (1.0f - s) * v_next;                // RESET_POTENTIAL = 0

        out[row]         = lam;     // spikes_lambda
        out[N + row]     = s;       // spiked_new
        out[2 * N + row] = v_new;   // v_new
    }
}

extern "C" void kernel_launch(void* const* d_in, const int* in_sizes, int n_in,
                              void* d_out, int out_size, void* d_ws, size_t ws_size,
                              hipStream_t stream) {
    const int N = in_sizes[0];
    const float* I_ext     = (const float*)d_in[0];
    const float* w         = (const float*)d_in[1];
    const float* v         = (const float*)d_in[2];
    const float* spiked    = (const float*)d_in[3];
    const float* tss       = (const float*)d_in[4];
    const float* theta_v   = (const float*)d_in[5];
    const float* tau_m     = (const float*)d_in[6];
    const float* tau_s     = (const float*)d_in[7];
    const float* tau_theta = (const float*)d_in[8];
    const float* J_theta   = (const float*)d_in[9];
    const float* E_L       = (const float*)d_in[10];
    const float* c         = (const float*)d_in[11];
    const float* Delta_u   = (const float*)d_in[12];
    const float* theta_inf = (const float*)d_in[13];
    float* out = (float*)d_out;
    float* eps = (float*)d_ws;   // N floats of scratch

    hipLaunchKernelGGL(eps_kernel, dim3((N + 255) / 256), dim3(256), 0, stream,
                       tss, tau_s, eps, N);
    hipLaunchKernelGGL(row_update_kernel, dim3((N + 3) / 4), dim3(256), 0, stream,
                       w, eps, I_ext, v, spiked, tss, theta_v, tau_m, tau_theta,
                       J_theta, E_L, c, Delta_u, theta_inf, out, N);
}

// Round 3
// 321.255 us; speedup vs baseline: 1.1915x; 1.1865x over previous
//
#include <hip/hip_runtime.h>
#include <stdint.h>

// ---------------------------------------------------------------------------
// JAX Threefry-2x32 (20 rounds), key = jax.random.key(42) -> (k0,k1) = (0,42)
// ---------------------------------------------------------------------------
__device__ __forceinline__ unsigned int rotl32(unsigned int x, unsigned int d) {
    return (x << d) | (x >> (32u - d));
}

__device__ __forceinline__ void threefry2x32_key0_42(unsigned int c0, unsigned int c1,
                                                     unsigned int& o0, unsigned int& o1) {
    const unsigned int ks0 = 0u;
    const unsigned int ks1 = 42u;
    const unsigned int ks2 = 0x1BD11BDAu ^ 0u ^ 42u;
    unsigned int x0 = c0 + ks0;
    unsigned int x1 = c1 + ks1;
#define TF_RND(r) { x0 += x1; x1 = rotl32(x1, (r)); x1 ^= x0; }
    TF_RND(13) TF_RND(15) TF_RND(26) TF_RND(6)
    x0 += ks1; x1 += ks2 + 1u;
    TF_RND(17) TF_RND(29) TF_RND(16) TF_RND(24)
    x0 += ks2; x1 += ks0 + 2u;
    TF_RND(13) TF_RND(15) TF_RND(26) TF_RND(6)
    x0 += ks0; x1 += ks1 + 3u;
    TF_RND(17) TF_RND(29) TF_RND(16) TF_RND(24)
    x0 += ks1; x1 += ks2 + 4u;
    TF_RND(13) TF_RND(15) TF_RND(26) TF_RND(6)
    x0 += ks2; x1 += ks0 + 5u;
#undef TF_RND
    o0 = x0; o1 = x1;
}

// jax_threefry_partitionable=True, bit_width=32: bits[n] = o0 ^ o1, counter (0, n)
__device__ __forceinline__ float jax_uniform_u01(unsigned int n) {
    unsigned int o0, o1;
    threefry2x32_key0_42(0u, n, o0, o1);
    unsigned int bits = o0 ^ o1;
    unsigned int fb = (bits >> 9) | 0x3F800000u;
    float u = __uint_as_float(fb) - 1.0f;
    return fmaxf(u, 0.0f);
}

// ---------------------------------------------------------------------------
// Kernel 1: eps[j] = (1+tanh(t))*exp(-t/tau_s)/tau_s, plus per-1024-element
// "any nonzero" flags (one block per chunk; ballot + LDS reduce, no atomics).
// SNN-domain sparsity: eps underflows to exactly 0 for neurons that haven't
// spiked recently — flagged chunks let the matvec skip those w columns.
// ---------------------------------------------------------------------------
__global__ __launch_bounds__(1024) void eps_flags_kernel(
    const float* __restrict__ tss,
    const float* __restrict__ tau_s,
    float* __restrict__ eps,
    int* __restrict__ flags, int N) {
    const int i = blockIdx.x * 1024 + threadIdx.x;
    float e = 0.0f;
    if (i < N) {
        float t  = tss[i] - 1.0f;   // DELTA_DELAY = 1.0
        float ts = tau_s[i];
        e = (1.0f + tanhf(t)) * expf(-t / ts) / ts;
        eps[i] = e;
    }
    // chunk-level any-nonzero: per-wave ballot -> LDS -> thread 0
    unsigned long long m = __ballot(e != 0.0f);
    __shared__ int wany[16];
    const int wid = threadIdx.x >> 6;
    if ((threadIdx.x & 63) == 0) wany[wid] = (m != 0ull) ? 1 : 0;
    __syncthreads();
    if (threadIdx.x == 0) {
        int any = 0;
        #pragma unroll
        for (int k = 0; k < 16; ++k) any |= wany[k];
        flags[blockIdx.x] = any;
    }
}

// ---------------------------------------------------------------------------
// Kernel 2: one wave per row (4 rows / 256-thread block). Chunk loop over
// 1024-element (256 x float4) chunks of the row; wave-uniform flag check
// skips chunks whose eps slice is entirely zero. Dense eps -> identical to
// the full unrolled matvec plus one uniform branch per chunk.
// ---------------------------------------------------------------------------
__global__ __launch_bounds__(256) void row_update_kernel(
    const float* __restrict__ w,
    const float* __restrict__ eps,
    const int* __restrict__ flags,
    const float* __restrict__ I_ext,
    const float* __restrict__ v,
    const float* __restrict__ spiked,
    const float* __restrict__ tss,
    const float* __restrict__ theta_v,
    const float* __restrict__ tau_m,
    const float* __restrict__ tau_theta,
    const float* __restrict__ J_theta,
    const float* __restrict__ E_L,
    const float* __restrict__ c,
    const float* __restrict__ Delta_u,
    const float* __restrict__ theta_inf,
    float* __restrict__ out, int N) {

    const int wid  = threadIdx.x >> 6;        // wave id within block: 0..3
    const int lane = threadIdx.x & 63;
    const int row  = blockIdx.x * 4 + wid;
    if (row >= N) return;

    const float4* __restrict__ wrow = (const float4*)(w + (size_t)row * (size_t)N);
    const float4* __restrict__ e4   = (const float4*)eps;
    const int n4      = N >> 2;               // float4 elements per row
    const int nchunks = (N + 1023) >> 10;     // 1024-element chunks

    float a0 = 0.0f, a1 = 0.0f, a2 = 0.0f, a3 = 0.0f;
    for (int ch = 0; ch < nchunks; ++ch) {
        if (flags[ch] == 0) continue;         // wave-uniform skip of zero chunk
        const int base = (ch << 8) + lane;    // 256 float4s per chunk
        if (base < n4) {
            float4 wv = wrow[base]; float4 ev = e4[base];
            a0 = fmaf(wv.x, ev.x, fmaf(wv.y, ev.y, fmaf(wv.z, ev.z, fmaf(wv.w, ev.w, a0))));
        }
        if (base + 64 < n4) {
            float4 wv = wrow[base + 64]; float4 ev = e4[base + 64];
            a1 = fmaf(wv.x, ev.x, fmaf(wv.y, ev.y, fmaf(wv.z, ev.z, fmaf(wv.w, ev.w, a1))));
        }
        if (base + 128 < n4) {
            float4 wv = wrow[base + 128]; float4 ev = e4[base + 128];
            a2 = fmaf(wv.x, ev.x, fmaf(wv.y, ev.y, fmaf(wv.z, ev.z, fmaf(wv.w, ev.w, a2))));
        }
        if (base + 192 < n4) {
            float4 wv = wrow[base + 192]; float4 ev = e4[base + 192];
            a3 = fmaf(wv.x, ev.x, fmaf(wv.y, ev.y, fmaf(wv.z, ev.z, fmaf(wv.w, ev.w, a3))));
        }
    }
    float acc = (a0 + a1) + (a2 + a3);

    // wave-wide (64-lane) reduction — no LDS, no barrier
    #pragma unroll
    for (int off = 32; off > 0; off >>= 1)
        acc += __shfl_down(acc, off, 64);

    if (lane == 0) {
        // zero-diagonal correction; skip the scattered diag load when eps[row]==0
        float er = eps[row];
        float I_syn = acc;
        if (er != 0.0f) I_syn -= w[(size_t)row * (size_t)N + row] * er;

        float th = theta_v[row] +
                   (theta_inf[row] - theta_v[row] + J_theta[row] * spiked[row]) / tau_theta[row];
        float v_next = v[row] + (E_L[row] - v[row] + I_ext[row]) / tau_m[row] + I_syn;

        float notref = (tss[row] > 2.0f) ? 1.0f : 0.0f;   // T_REFRACTORY = 2.0
        float lam = notref * c[row] * expf((v_next - th) / Delta_u[row]);
        lam = fminf(fmaxf(lam, 0.0f), 1.0f);

        float u = jax_uniform_u01((unsigned int)row);
        float s = (u < lam) ? 1.0f : 0.0f;
        float v_new = (1.0f - s) * v_next;                // RESET_POTENTIAL = 0

        out[row]         = lam;     // spikes_lambda
        out[N + row]     = s;       // spiked_new
        out[2 * N + row] = v_new;   // v_new
    }
}

extern "C" void kernel_launch(void* const* d_in, const int* in_sizes, int n_in,
                              void* d_out, int out_size, void* d_ws, size_t ws_size,
                              hipStream_t stream) {
    const int N = in_sizes[0];
    const float* I_ext     = (const float*)d_in[0];
    const float* w         = (const float*)d_in[1];
    const float* v         = (const float*)d_in[2];
    const float* spiked    = (const float*)d_in[3];
    const float* tss       = (const float*)d_in[4];
    const float* theta_v   = (const float*)d_in[5];
    const float* tau_m     = (const float*)d_in[6];
    const float* tau_s     = (const float*)d_in[7];
    const float* tau_theta = (const float*)d_in[8];
    const float* J_theta   = (const float*)d_in[9];
    const float* E_L       = (const float*)d_in[10];
    const float* c         = (const float*)d_in[11];
    const float* Delta_u   = (const float*)d_in[12];
    const float* theta_inf = (const float*)d_in[13];
    float* out = (float*)d_out;
    float* eps   = (float*)d_ws;                 // N floats
    int*   flags = (int*)((char*)d_ws + (size_t)N * sizeof(float));  // ceil(N/1024) ints

    const int nchunks = (N + 1023) / 1024;
    hipLaunchKernelGGL(eps_flags_kernel, dim3(nchunks), dim3(1024), 0, stream,
                       tss, tau_s, eps, flags, N);
    hipLaunchKernelGGL(row_update_kernel, dim3((N + 3) / 4), dim3(256), 0, stream,
                       w, eps, flags, I_ext, v, spiked, tss, theta_v, tau_m, tau_theta,
                       J_theta, E_L, c, Delta_u, theta_inf, out, N);
}